// Round 2
// baseline (595.219 us; speedup 1.0000x reference)
//
#include <hip/hip_runtime.h>

// MultiAttention: B=32768, HOP=32, D=64.
// score[b,h] = sum_d tanh((rel@w_r)[d])*va[64+d] + tanh((nbr@w_t)[d])*va[128+d]; softmax over h.
// R2: W-frags in LDS (occupancy 1.6->3 waves/SIMD), DPP column reduction (no lgkm chains),
//     all 16 batch loads issued up front.

typedef short bf16x8 __attribute__((ext_vector_type(8)));
typedef float f32x4 __attribute__((ext_vector_type(4)));

#define NB   32768
#define NHOP 32
#define ND   64

__device__ __forceinline__ float tanh_fast(float x) {
  float cx = fminf(fmaxf(x, -20.f), 20.f);
  float e2 = __expf(2.f * cx);
  return (e2 - 1.f) * __builtin_amdgcn_rcpf(e2 + 1.f);
}

__device__ __forceinline__ void split2(float4 v0, float4 v1, bf16x8 &hi, bf16x8 &lo) {
  float xs[8] = {v0.x, v0.y, v0.z, v0.w, v1.x, v1.y, v1.z, v1.w};
#pragma unroll
  for (int j = 0; j < 8; ++j) {
    unsigned u = __builtin_bit_cast(unsigned, xs[j]);
    hi[j] = (short)(u >> 16);
    float hif = __builtin_bit_cast(float, u & 0xffff0000u);
    lo[j] = (short)(__builtin_bit_cast(unsigned, xs[j] - hif) >> 16);
  }
}

// sum across the 16 lanes of a DPP row (l15 groups) — pure VALU, no LDS pipe.
__device__ __forceinline__ float dpp_reduce16(float x) {
  int t;
  t = __builtin_amdgcn_update_dpp(0, __builtin_bit_cast(int, x), 0xB1, 0xf, 0xf, true);   // quad_perm xor1
  x += __builtin_bit_cast(float, t);
  t = __builtin_amdgcn_update_dpp(0, __builtin_bit_cast(int, x), 0x4E, 0xf, 0xf, true);   // quad_perm xor2
  x += __builtin_bit_cast(float, t);
  t = __builtin_amdgcn_update_dpp(0, __builtin_bit_cast(int, x), 0x141, 0xf, 0xf, true);  // row_half_mirror
  x += __builtin_bit_cast(float, t);
  t = __builtin_amdgcn_update_dpp(0, __builtin_bit_cast(int, x), 0x140, 0xf, 0xf, true);  // row_mirror
  x += __builtin_bit_cast(float, t);
  return x;
}

__global__ __launch_bounds__(256, 3)
void attn_fused(const float* __restrict__ rel, const float* __restrict__ nbr,
                const float* __restrict__ wr, const float* __restrict__ wt,
                const float* __restrict__ va, float* __restrict__ out, int nwaves) {
  // W B-fragments, hi+lo, both matrices: 32 frags x 64 lanes x 16 B = 32 KB.
  // combo = (mat*2+c)*4+nt; frag f = combo*2 + half. One contiguous 1 KB row per frag
  // -> ds_read_b128 with zero bank conflicts.
  __shared__ bf16x8 wlds[32][64];

  const int lane = threadIdx.x & 63;
  const int wv   = threadIdx.x >> 6;
  const int wid  = (blockIdx.x * blockDim.x + threadIdx.x) >> 6;
  const int l15  = lane & 15;   // A row m / C col
  const int lg   = lane >> 4;   // A k-group / C row group

  // ---- build W fragments cooperatively (4 combos per wave) ----
#pragma unroll
  for (int i = 0; i < 4; ++i) {
    int combo = wv * 4 + i;
    int mat = combo >> 3, c = (combo >> 2) & 1, nt = combo & 3;
    const float* W = mat ? wt : wr;
    bf16x8 hi, lo;
#pragma unroll
    for (int j = 0; j < 8; ++j) {
      float x = W[(c * 32 + lg * 8 + j) * 64 + nt * 16 + l15];
      unsigned u = __builtin_bit_cast(unsigned, x);
      hi[j] = (short)(u >> 16);
      float hif = __builtin_bit_cast(float, u & 0xffff0000u);
      lo[j] = (short)(__builtin_bit_cast(unsigned, x - hif) >> 16);
    }
    wlds[combo * 2][lane]     = hi;
    wlds[combo * 2 + 1][lane] = lo;
  }
  __syncthreads();

  float vaa[2][4];
#pragma unroll
  for (int nt = 0; nt < 4; ++nt) {
    vaa[0][nt] = va[64 + nt * 16 + l15];
    vaa[1][nt] = va[128 + nt * 16 + l15];
  }

  for (int b = wid; b < NB; b += nwaves) {
    // ---- issue all 16 global loads up front (16 KB/wave in flight) ----
    float4 raw[2][2][4];  // [mat][tt][quarter]
#pragma unroll
    for (int mat = 0; mat < 2; ++mat) {
      const float* src = mat ? nbr : rel;
#pragma unroll
      for (int tt = 0; tt < 2; ++tt) {
        const float* base = src + ((size_t)b * NHOP + tt * 16 + l15) * ND + lg * 8;
        raw[mat][tt][0] = *(const float4*)(base);
        raw[mat][tt][1] = *(const float4*)(base + 4);
        raw[mat][tt][2] = *(const float4*)(base + 32);
        raw[mat][tt][3] = *(const float4*)(base + 36);
      }
    }

    float sc[2][4] = {{0.f, 0.f, 0.f, 0.f}, {0.f, 0.f, 0.f, 0.f}};

#pragma unroll
    for (int mat = 0; mat < 2; ++mat) {
      bf16x8 ahi[2][2], alo[2][2];  // [tt][c]
#pragma unroll
      for (int tt = 0; tt < 2; ++tt) {
        split2(raw[mat][tt][0], raw[mat][tt][1], ahi[tt][0], alo[tt][0]);
        split2(raw[mat][tt][2], raw[mat][tt][3], ahi[tt][1], alo[tt][1]);
      }
      f32x4 acc[2][4];
#pragma unroll
      for (int tt = 0; tt < 2; ++tt)
#pragma unroll
        for (int nt = 0; nt < 4; ++nt) acc[tt][nt] = (f32x4){0.f, 0.f, 0.f, 0.f};

#pragma unroll
      for (int c = 0; c < 2; ++c)
#pragma unroll
        for (int nt = 0; nt < 4; ++nt) {
          int combo = (mat * 2 + c) * 4 + nt;
          bf16x8 whi = wlds[combo * 2][lane];
          bf16x8 wlo = wlds[combo * 2 + 1][lane];
#pragma unroll
          for (int tt = 0; tt < 2; ++tt) {
            acc[tt][nt] = __builtin_amdgcn_mfma_f32_16x16x32_bf16(ahi[tt][c], whi, acc[tt][nt], 0, 0, 0);
            acc[tt][nt] = __builtin_amdgcn_mfma_f32_16x16x32_bf16(alo[tt][c], whi, acc[tt][nt], 0, 0, 0);
            acc[tt][nt] = __builtin_amdgcn_mfma_f32_16x16x32_bf16(ahi[tt][c], wlo, acc[tt][nt], 0, 0, 0);
          }
        }

#pragma unroll
      for (int tt = 0; tt < 2; ++tt)
#pragma unroll
        for (int nt = 0; nt < 4; ++nt)
#pragma unroll
          for (int rr = 0; rr < 4; ++rr)
            sc[tt][rr] += tanh_fast(acc[tt][nt][rr]) * vaa[mat][nt];
    }

    // column reduction across the 16 l15 lanes — DPP, VALU-only
#pragma unroll
    for (int tt = 0; tt < 2; ++tt)
#pragma unroll
      for (int rr = 0; rr < 4; ++rr)
        sc[tt][rr] = dpp_reduce16(sc[tt][rr]);

    // softmax over 32 hops (rows lg*4+rr + 16*tt), cross-group via shfl
    float smax = fmaxf(fmaxf(sc[0][0], sc[0][1]), fmaxf(sc[0][2], sc[0][3]));
    smax = fmaxf(smax, fmaxf(fmaxf(sc[1][0], sc[1][1]), fmaxf(sc[1][2], sc[1][3])));
    smax = fmaxf(smax, __shfl_xor(smax, 16, 64));
    smax = fmaxf(smax, __shfl_xor(smax, 32, 64));

    float e[2][4];
    float ssum = 0.f;
#pragma unroll
    for (int tt = 0; tt < 2; ++tt)
#pragma unroll
      for (int rr = 0; rr < 4; ++rr) {
        e[tt][rr] = __expf(sc[tt][rr] - smax);
        ssum += e[tt][rr];
      }
    ssum += __shfl_xor(ssum, 16, 64);
    ssum += __shfl_xor(ssum, 32, 64);
    float inv = __builtin_amdgcn_rcpf(ssum);

    if (l15 == 0) {
      float* ob = out + (size_t)b * NHOP;
      float4 o0 = {e[0][0] * inv, e[0][1] * inv, e[0][2] * inv, e[0][3] * inv};
      float4 o1 = {e[1][0] * inv, e[1][1] * inv, e[1][2] * inv, e[1][3] * inv};
      *(float4*)(ob + lg * 4)      = o0;
      *(float4*)(ob + 16 + lg * 4) = o1;
    }
  }
}

extern "C" void kernel_launch(void* const* d_in, const int* in_sizes, int n_in,
                              void* d_out, int out_size, void* d_ws, size_t ws_size,
                              hipStream_t stream) {
  // inputs: 0 entity (dead), 1 relation, 2 neighbor, 3 w_h (dead), 4 w_t, 5 w_r, 6 v_a
  const float* rel = (const float*)d_in[1];
  const float* nbr = (const float*)d_in[2];
  const float* wt  = (const float*)d_in[4];
  const float* wr  = (const float*)d_in[5];
  const float* va  = (const float*)d_in[6];
  float* out = (float*)d_out;

  const int blocks = 2048;                 // 8192 waves, 4 batches each
  attn_fused<<<blocks, 256, 0, stream>>>(rel, nbr, wr, wt, va, out, blocks * 4);
}